// Round 12
// baseline (203.040 us; speedup 1.0000x reference)
//
#include <hip/hip_runtime.h>
#include <hip/hip_bf16.h>

typedef _Float16 half8 __attribute__((ext_vector_type(8)));
typedef float f32x4 __attribute__((ext_vector_type(4)));
typedef unsigned uint4e __attribute__((ext_vector_type(4)));
typedef unsigned uint2e __attribute__((ext_vector_type(2)));

#define B_ 16
#define C_ 256
#define D_ 128
#define H_ 64
#define W_ 64
#define N_ 4096   // H*W
#define M_ 1024   // (H/2)*(W/2)
#define NCH 32    // M/32 key chunks

// workspace layout (bytes)
static constexpr size_t WS_PHI   = 0;                                  // fp16 [B][M][C]   8 MB
static constexpr size_t WS_GPOOL = WS_PHI   + (size_t)B_*M_*C_*2;      // fp16 [B][D][M]   4 MB
static constexpr size_t WS_Y     = WS_GPOOL + (size_t)B_*D_*M_*2;      // fp16 [B][N][D]  16 MB
static constexpr size_t WS_BNSUM = WS_Y     + (size_t)B_*N_*D_*2;      // f32  [C]
static constexpr size_t WS_BNSSQ = WS_BNSUM + (size_t)C_*4;            // f32  [C]
static constexpr size_t WS_PSUM  = WS_BNSSQ + (size_t)C_*4;            // f32  [1024][256] 1MB
static constexpr size_t WS_PSSQ  = WS_PSUM  + (size_t)1024*256*4;      // f32  [1024][256] 1MB
static constexpr size_t WS_GW16  = WS_PSSQ  + (size_t)1024*256*4;      // fp16 [D][C] 64KB
static constexpr size_t WS_WW16  = WS_GW16  + (size_t)D_*C_*2;         // fp16 [C][D] 64KB

typedef __attribute__((address_space(3))) void lds_vt;
typedef const __attribute__((address_space(1))) void gbl_vt;

__device__ __forceinline__ void gl2lds16(const void* g, void* s) {
  __builtin_amdgcn_global_load_lds((gbl_vt*)g, (lds_vt*)s, 16, 0, 0);
}

__device__ __forceinline__ unsigned pkrtz(float a, float b) {
  auto v = __builtin_amdgcn_cvt_pkrtz(a, b);   // __fp16 ext_vector(2)
  return __builtin_bit_cast(unsigned, v);
}

// xor-32 lane exchange on the VALU pipe (permlane32_swap) instead of LDS.
__device__ __forceinline__ unsigned xor32_swap(unsigned v) {
#if __has_builtin(__builtin_amdgcn_permlane32_swap)
  auto pr = __builtin_amdgcn_permlane32_swap(v, v, false, false);
  uint2e p = __builtin_bit_cast(uint2e, pr);
  return (threadIdx.x & 32) ? p[0] : p[1];
#else
  return __shfl_xor(v, 32, 64);
#endif
}
__device__ __forceinline__ float xor32f(float v) {
  return __builtin_bit_cast(float, xor32_swap(__builtin_bit_cast(unsigned, v)));
}

// ---------------------------------------------------------------------------
// P0: convert weights to fp16 once. gw16[d][c], ww16[c][d].
// ---------------------------------------------------------------------------
__global__ __launch_bounds__(256) void conv16_kernel(
    const float* __restrict__ gw, const float* __restrict__ ww,
    _Float16* __restrict__ gw16, _Float16* __restrict__ ww16) {
  const int i = blockIdx.x*256 + threadIdx.x;   // 0..32767
  gw16[i] = (_Float16)gw[i];
  ww16[i] = (_Float16)ww[i];
}

// ---------------------------------------------------------------------------
// P1+P2 fused: LDS-staged x slab (fp16 [256c][130n] padded), coalesced float4
// staging. phi = fp16(maxpool2x2(x)); gpool = fp16(maxpool2x2(g_w*.x)+g_b).
// (verified round 10)
// ---------------------------------------------------------------------------
__global__ __launch_bounds__(512, 4) void fused_pre_kernel(
    const float* __restrict__ x, const _Float16* __restrict__ gw16,
    const float* __restrict__ g_b, _Float16* __restrict__ phi,
    _Float16* __restrict__ gpool) {
  const int i = blockIdx.x;            // image row-pair (rows 2i, 2i+1)
  const int b = blockIdx.y;
  const int t = threadIdx.x;
  const int w = t >> 6, l = t & 63, gq = (l >> 4) & 3, c16 = l & 15;
  const int wn = w & 3, wd = w >> 2;

  __shared__ _Float16 x_s[256][130];   // 65 KB; odd dword pitch -> all banks

  {
    const float* xb = x + (size_t)b*C_*N_ + (size_t)i*128;
#pragma unroll
    for (int it = 0; it < 16; ++it) {
      const int id = it*512 + t;
      const int c = id >> 5, nq = id & 31;
      float4 u = *(const float4*)(xb + (size_t)c*N_ + nq*4);
      unsigned* dst = (unsigned*)&x_s[c][nq*4];
      dst[0] = pkrtz(u.x, u.y);
      dst[1] = pkrtz(u.z, u.w);
    }
  }
  __syncthreads();

  f32x4 acc[4][2];
#pragma unroll
  for (int ds = 0; ds < 4; ++ds) {
    acc[ds][0] = (f32x4){0.f,0.f,0.f,0.f};
    acc[ds][1] = (f32x4){0.f,0.f,0.f,0.f};
  }

  const int nn0 = wn*16 + c16;
  const int mrow = i*32 + wn*8 + (c16 >> 1);

  for (int kk = 0; kk < 8; ++kk) {
    const int c0 = kk*32 + gq*8;
    half8 bf0, bf1;
#pragma unroll
    for (int j = 0; j < 8; ++j) {
      bf0[j] = x_s[c0 + j][nn0];
      bf1[j] = x_s[c0 + j][nn0 + 64];
    }
    if (wd == 0) {
      half8 pk_;
#pragma unroll
      for (int j = 0; j < 8; ++j) {
        float v = fmaxf((float)bf0[j], (float)bf1[j]);
        v = fmaxf(v, __shfl_xor(v, 1, 64));
        pk_[j] = (_Float16)v;
      }
      if (!(l & 1))
        *(half8*)(phi + ((size_t)b*M_ + mrow)*C_ + c0) = pk_;
    }
#pragma unroll
    for (int ds = 0; ds < 4; ++ds) {
      half8 af = *(const half8*)(gw16 + (size_t)((wd*4 + ds)*16 + c16)*C_ + c0);
      acc[ds][0] = __builtin_amdgcn_mfma_f32_16x16x32_f16(af, bf0, acc[ds][0], 0, 0, 0);
      acc[ds][1] = __builtin_amdgcn_mfma_f32_16x16x32_f16(af, bf1, acc[ds][1], 0, 0, 0);
    }
  }

#pragma unroll
  for (int ds = 0; ds < 4; ++ds) {
#pragma unroll
    for (int r = 0; r < 4; ++r) {
      const int d = (wd*4 + ds)*16 + gq*4 + r;
      float v = fmaxf(acc[ds][0][r], acc[ds][1][r]);
      v = fmaxf(v, __shfl_xor(v, 1, 64));
      if (!(l & 1))
        gpool[((size_t)b*D_ + d)*M_ + mrow] = (_Float16)(v + g_b[d]);
    }
  }
}

// ---------------------------------------------------------------------------
// in-register P -> PV A-fragment build (xor16 via ds_swizzle, xor32 via VALU)
// ---------------------------------------------------------------------------
__device__ __forceinline__ half8 build_pa(const float p0[4], const float p1[4], int gq) {
  unsigned d0 = pkrtz(p0[0], p0[1]);
  unsigned d1 = pkrtz(p0[2], p0[3]);
  unsigned e0 = pkrtz(p1[0], p1[1]);
  unsigned e1 = pkrtz(p1[2], p1[3]);
  unsigned D0 = __shfl_xor(d0, 16, 64), D1 = __shfl_xor(d1, 16, 64);
  unsigned E0 = __shfl_xor(e0, 16, 64), E1 = __shfl_xor(e1, 16, 64);
  const bool lo = gq < 2;
  unsigned s0 = lo ? e0 : d0, s1 = lo ? e1 : d1;
  unsigned s2 = lo ? E0 : D0, s3 = lo ? E1 : D1;
  unsigned R0 = xor32_swap(s0), R1 = xor32_swap(s1);
  unsigned R2 = xor32_swap(s2), R3 = xor32_swap(s3);
  uint4e u;
  u[0] = gq==0 ? d0 : gq==1 ? R2 : gq==2 ? R0 : E0;
  u[1] = gq==0 ? d1 : gq==1 ? R3 : gq==2 ? R1 : E1;
  u[2] = gq==0 ? D0 : gq==1 ? R0 : gq==2 ? R2 : e0;
  u[3] = gq==0 ? D1 : gq==1 ? R1 : gq==2 ? R3 : e1;
  return __builtin_bit_cast(half8, u);
}

// ---------------------------------------------------------------------------
// P3: flash attention v6. 4 waves x 32 q-rows = 128 q/block, 256 threads,
// grid (32,16) = 2 blocks/CU = 8 waves/CU (2/SIMD, 256-VGPR budget).
// Halves QK A-fragment LDS reads per q vs v5 (the 74%-busy pipe).
// Triple-buffered LDS (72KB) -> ONE barrier/chunk; 6 stage-loads/wave ->
// counted vmcnt(6). Swapped QK, in-reg softmax, defer-max THR=8.
// ---------------------------------------------------------------------------
__global__ __launch_bounds__(256, 2) void attn_kernel(
    const float* __restrict__ x, const _Float16* __restrict__ phi,
    const _Float16* __restrict__ gpool, _Float16* __restrict__ y) {
  const int nt = blockIdx.x;           // 0..31
  const int b  = blockIdx.y;
  const int t  = threadIdx.x;
  const int w = t >> 6, l = t & 63, gq = (l >> 4) & 3, c16 = l & 15;
  const int nw = nt*128 + w*32;

  __shared__ alignas(16) _Float16 phi_s[3][32*256];   // 16KB x 3
  __shared__ alignas(16) _Float16 gp_s[3][128*32];    // 8KB x 3

  // Q fragments (B-operand): rows nw + rt*16 + c16, K=256 in 8 kk-steps
  half8 qf[2][8];
#pragma unroll
  for (int rt = 0; rt < 2; ++rt) {
    const int nq = nw + rt*16 + c16;
#pragma unroll
    for (int kk = 0; kk < 8; ++kk) {
      const int cb = kk*32 + gq*8;
      half8 q;
#pragma unroll
      for (int j = 0; j < 8; ++j) q[j] = (_Float16)x[((size_t)b*C_ + cb + j)*N_ + nq];
      qf[rt][kk] = q;
    }
  }

  f32x4 yacc[2][8];
#pragma unroll
  for (int rt = 0; rt < 2; ++rt)
#pragma unroll
    for (int ds = 0; ds < 8; ++ds) yacc[rt][ds] = (f32x4){0.f,0.f,0.f,0.f};
  float m_run[2] = {-INFINITY, -INFINITY};
  float l_run[2] = {0.f, 0.f};

  const int lhi = l >> 5, l31 = l & 31;

  auto stage = [&](int buf, int ch2) {
    const int m0 = ch2 * 32;
    // phi chunk 16KB = 16 slots (4/wave). plane p = 2j+lhi, row m = l31.
#pragma unroll
    for (int jj = 0; jj < 4; ++jj) {
      const int j = w*4 + jj;
      const char* src = (const char*)phi + ((size_t)(b*M_ + m0 + l31))*512 + (2*j + lhi)*16;
      gl2lds16(src, (char*)&phi_s[buf][0] + j*1024);
    }
    // gp chunk 8KB = 8 slots (2/wave). plane = j>>1, d = (j&1)*64 + l.
#pragma unroll
    for (int jj = 0; jj < 2; ++jj) {
      const int j = w*2 + jj;
      const char* src = (const char*)gpool + (((size_t)(b*D_ + (j&1)*64 + l))*M_ + m0)*2 + (j>>1)*16;
      gl2lds16(src, (char*)&gp_s[buf][0] + j*1024);
    }
  };

  stage(0, 0);
  stage(1, 1);

  const char* pAbase = (const char*)&phi_s[0][0] + gq*512 + c16*16;
  const char* pBbase = (const char*)&gp_s[0][0] + gq*2048 + c16*16;

  for (int ch = 0; ch < NCH; ++ch) {
    const int cur = ch % 3;
    if (ch < NCH - 1) {
      asm volatile("s_waitcnt vmcnt(6)" ::: "memory");   // stage(ch) landed
    } else {
      asm volatile("s_waitcnt vmcnt(0)" ::: "memory");
    }
    __builtin_amdgcn_s_barrier();
    asm volatile("" ::: "memory");

    // ---- QK^T swapped: fS[rt][mt] = S[m = mt*16+gq*4+r][q-col = c16]
    f32x4 fS[2][2];
    fS[0][0] = (f32x4){0.f,0.f,0.f,0.f}; fS[0][1] = (f32x4){0.f,0.f,0.f,0.f};
    fS[1][0] = (f32x4){0.f,0.f,0.f,0.f}; fS[1][1] = (f32x4){0.f,0.f,0.f,0.f};
    const char* pA = pAbase + cur*16384;
    __builtin_amdgcn_s_setprio(1);
#pragma unroll
    for (int kk = 0; kk < 8; ++kk) {
      half8 a0 = *(const half8*)(pA + kk*2048);        // mt=0 rows
      half8 a1 = *(const half8*)(pA + kk*2048 + 256);  // mt=1 rows
      fS[0][0] = __builtin_amdgcn_mfma_f32_16x16x32_f16(a0, qf[0][kk], fS[0][0], 0, 0, 0);
      fS[1][0] = __builtin_amdgcn_mfma_f32_16x16x32_f16(a0, qf[1][kk], fS[1][0], 0, 0, 0);
      fS[0][1] = __builtin_amdgcn_mfma_f32_16x16x32_f16(a1, qf[0][kk], fS[0][1], 0, 0, 0);
      fS[1][1] = __builtin_amdgcn_mfma_f32_16x16x32_f16(a1, qf[1][kk], fS[1][1], 0, 0, 0);
    }
    __builtin_amdgcn_s_setprio(0);

    // ---- online softmax (per q-col, lane-local) + defer-max
    float cm[2];
#pragma unroll
    for (int rt = 0; rt < 2; ++rt) {
      float cmax = fS[rt][0][0];
#pragma unroll
      for (int mt = 0; mt < 2; ++mt)
#pragma unroll
        for (int r = 0; r < 4; ++r) cmax = fmaxf(cmax, fS[rt][mt][r]);
      cmax = fmaxf(cmax, __shfl_xor(cmax, 16, 64));
      cmax = fmaxf(cmax, xor32f(cmax));
      cm[rt] = cmax;
    }
    const float grow = fmaxf(cm[0] - m_run[0], cm[1] - m_run[1]);
    if (__any(grow > 8.0f)) {     // slow path: rescale
#pragma unroll
      for (int rt = 0; rt < 2; ++rt) {
        const float mn = fmaxf(m_run[rt], cm[rt]);
        const float sc = __expf(m_run[rt] - mn);
        m_run[rt] = mn;
        l_run[rt] *= sc;
        const int sci = __float_as_int(sc);
#pragma unroll
        for (int r = 0; r < 4; ++r) {
          const float scn = __int_as_float(__builtin_amdgcn_ds_bpermute(4*(gq*4 + r), sci));
#pragma unroll
          for (int ds = 0; ds < 8; ++ds) yacc[rt][ds][r] *= scn;
        }
      }
    }
    half8 pa[2];
#pragma unroll
    for (int rt = 0; rt < 2; ++rt) {
      float p0[4], p1[4];
      float rs = 0.f;
#pragma unroll
      for (int r = 0; r < 4; ++r) {
        p0[r] = __expf(fS[rt][0][r] - m_run[rt]);
        p1[r] = __expf(fS[rt][1][r] - m_run[rt]);
        rs += p0[r] + p1[r];
      }
      rs += __shfl_xor(rs, 16, 64);
      rs += xor32f(rs);
      l_run[rt] += rs;
      pa[rt] = build_pa(p0, p1, gq);
    }

    // ---- PV (V from LDS, conflict-free 16B-plane layout)
    const char* pB = pBbase + cur*8192;
    __builtin_amdgcn_s_setprio(1);
#pragma unroll
    for (int ds = 0; ds < 8; ++ds) {
      half8 bv = *(const half8*)(pB + ds*256);
      yacc[0][ds] = __builtin_amdgcn_mfma_f32_16x16x32_f16(pa[0], bv, yacc[0][ds], 0, 0, 0);
      yacc[1][ds] = __builtin_amdgcn_mfma_f32_16x16x32_f16(pa[1], bv, yacc[1][ds], 0, 0, 0);
    }
    __builtin_amdgcn_s_setprio(0);

    // ---- prefetch chunk ch+2 into buf (ch+2)%3
    if (ch + 2 < NCH) stage((ch + 2) % 3, ch + 2);
  }

  // epilogue: broadcast 1/l from q=c16 lanes to (gq,r) rows, write y fp16
#pragma unroll
  for (int rt = 0; rt < 2; ++rt) {
    const float inv = 1.0f / l_run[rt];
    const int invi = __float_as_int(inv);
#pragma unroll
    for (int r = 0; r < 4; ++r) {
      const float invn = __int_as_float(__builtin_amdgcn_ds_bpermute(4*(gq*4 + r), invi));
      const int n = nw + rt*16 + gq*4 + r;
      _Float16* yr = y + ((size_t)b*N_ + n)*D_ + c16;
#pragma unroll
      for (int ds = 0; ds < 8; ++ds) yr[ds*16] = (_Float16)(yacc[rt][ds][r] * invn);
    }
  }
}

// ---------------------------------------------------------------------------
// P4a: W-conv recompute -> per-(block,channel) partial sum/sumsq. No atomics.
// grid (64 n-tiles of 64 rows, 16 b) = 1024 blocks (4/CU). (verified r10)
// ---------------------------------------------------------------------------
__global__ __launch_bounds__(256) void stats_partial_kernel(
    const _Float16* __restrict__ y, const _Float16* __restrict__ ww16,
    const float* __restrict__ w_b, float* __restrict__ psum,
    float* __restrict__ pssq) {
  const int nt = blockIdx.x, b = blockIdx.y, t = threadIdx.x;
  const int w = t >> 6, l = t & 63, g = l >> 4, c16 = l & 15;
  const int n0 = nt*64;

  f32x4 acc[4][4];
#pragma unroll
  for (int a = 0; a < 4; ++a)
#pragma unroll
    for (int n = 0; n < 4; ++n) acc[a][n] = (f32x4){0.f,0.f,0.f,0.f};

#pragma unroll
  for (int kk = 0; kk < 4; ++kk) {
    const int d0 = kk*32 + g*8;
    half8 af[4];
#pragma unroll
    for (int cs = 0; cs < 4; ++cs)
      af[cs] = *(const half8*)(ww16 + (size_t)(w*64 + cs*16 + c16)*D_ + d0);
#pragma unroll
    for (int ns = 0; ns < 4; ++ns) {
      const int nn = n0 + ns*16 + c16;
      half8 bf = *(const half8*)&y[((size_t)b*N_ + nn)*D_ + d0];
#pragma unroll
      for (int cs = 0; cs < 4; ++cs)
        acc[cs][ns] = __builtin_amdgcn_mfma_f32_16x16x32_f16(af[cs], bf, acc[cs][ns], 0, 0, 0);
    }
  }

  const int blk = b*64 + nt;
#pragma unroll
  for (int cs = 0; cs < 4; ++cs)
#pragma unroll
    for (int r = 0; r < 4; ++r) {
      const int c = w*64 + cs*16 + g*4 + r;
      const float wb = w_b[c];
      float s = 0.f, q = 0.f;
#pragma unroll
      for (int ns = 0; ns < 4; ++ns) {
        const float v = acc[cs][ns][r] + wb;
        s += v; q += v*v;
      }
      s += __shfl_xor(s, 1, 64); s += __shfl_xor(s, 2, 64);
      s += __shfl_xor(s, 4, 64); s += __shfl_xor(s, 8, 64);
      q += __shfl_xor(q, 1, 64); q += __shfl_xor(q, 2, 64);
      q += __shfl_xor(q, 4, 64); q += __shfl_xor(q, 8, 64);
      if (c16 == 0) {
        psum[blk*C_ + c] = s;
        pssq[blk*C_ + c] = q;
      }
    }
}

// ---------------------------------------------------------------------------
// P4a2: reduce 1024 partials -> bnsum/bnssq. grid 8 blocks x 256t.
// ---------------------------------------------------------------------------
__global__ __launch_bounds__(256) void stats_reduce_kernel(
    const float* __restrict__ psum, const float* __restrict__ pssq,
    float* __restrict__ bnsum, float* __restrict__ bnssq) {
  const int t = threadIdx.x;
  const int ci = t & 31, bi = t >> 5;
  const int c = blockIdx.x*32 + ci;
  float s = 0.f, q = 0.f;
  for (int k = 0; k < 128; ++k) {
    const int row = bi + k*8;
    s += psum[row*C_ + c];
    q += pssq[row*C_ + c];
  }
  __shared__ float rs[8][32], rq[8][32];
  rs[bi][ci] = s; rq[bi][ci] = q;
  __syncthreads();
  if (bi == 0) {
    float S = 0.f, Q = 0.f;
#pragma unroll
    for (int k2 = 0; k2 < 8; ++k2) { S += rs[k2][ci]; Q += rq[k2][ci]; }
    bnsum[c] = S; bnssq[c] = Q;
  }
}

// ---------------------------------------------------------------------------
// P4b: W-conv recompute (fp16 y) + BatchNorm + residual -> out[b][c][n] f32
// grid (64 n-tiles of 64 rows, 16 b). (verified r10)
// ---------------------------------------------------------------------------
__global__ __launch_bounds__(256) void wconv_bn_kernel(
    const _Float16* __restrict__ y, const _Float16* __restrict__ ww16,
    const float* __restrict__ w_b, const float* __restrict__ bnsum,
    const float* __restrict__ bnssq, const float* __restrict__ gamma,
    const float* __restrict__ beta, const float* __restrict__ x,
    float* __restrict__ out) {
  const int nt = blockIdx.x, b = blockIdx.y, t = threadIdx.x;
  const int w = t >> 6, l = t & 63, g = l >> 4, c16 = l & 15;
  const int n0 = nt*64;

  f32x4 acc[4][4];
#pragma unroll
  for (int a = 0; a < 4; ++a)
#pragma unroll
    for (int n = 0; n < 4; ++n) acc[a][n] = (f32x4){0.f,0.f,0.f,0.f};

#pragma unroll
  for (int kk = 0; kk < 4; ++kk) {
    const int d0 = kk*32 + g*8;
    half8 af[4];
#pragma unroll
    for (int cs = 0; cs < 4; ++cs)
      af[cs] = *(const half8*)(ww16 + (size_t)(w*64 + cs*16 + c16)*D_ + d0);
#pragma unroll
    for (int ns = 0; ns < 4; ++ns) {
      const int nn = n0 + ns*16 + c16;
      half8 bf = *(const half8*)&y[((size_t)b*N_ + nn)*D_ + d0];
#pragma unroll
      for (int cs = 0; cs < 4; ++cs)
        acc[cs][ns] = __builtin_amdgcn_mfma_f32_16x16x32_f16(af[cs], bf, acc[cs][ns], 0, 0, 0);
    }
  }

  const float inv_cnt = 1.0f / (float)((size_t)B_ * N_);
#pragma unroll
  for (int cs = 0; cs < 4; ++cs) {
#pragma unroll
    for (int r = 0; r < 4; ++r) {
      const int c = w*64 + cs*16 + g*4 + r;
      const float wb  = w_b[c];
      const float mean = bnsum[c] * inv_cnt;
      const float var  = bnssq[c] * inv_cnt - mean*mean;
      const float istd = rsqrtf(var + 1e-5f);
      const float ga = gamma[c], be = beta[c];
#pragma unroll
      for (int ns = 0; ns < 4; ++ns) {
        const int n = n0 + ns*16 + c16;
        const size_t idx = ((size_t)b*C_ + c)*N_ + n;
        const float v = acc[cs][ns][r] + wb;
        out[idx] = (v - mean)*istd*ga + be + x[idx];
      }
    }
  }
}

// ---------------------------------------------------------------------------
extern "C" void kernel_launch(void* const* d_in, const int* in_sizes, int n_in,
                              void* d_out, int out_size, void* d_ws, size_t ws_size,
                              hipStream_t stream) {
  const float* x     = (const float*)d_in[0];
  const float* g_w   = (const float*)d_in[1];
  const float* g_b   = (const float*)d_in[2];
  const float* w_w   = (const float*)d_in[3];
  const float* w_b   = (const float*)d_in[4];
  const float* gamma = (const float*)d_in[5];
  const float* beta  = (const float*)d_in[6];
  float* out = (float*)d_out;

  char* ws = (char*)d_ws;
  _Float16* phi   = (_Float16*)(ws + WS_PHI);
  _Float16* gpool = (_Float16*)(ws + WS_GPOOL);
  _Float16* yb    = (_Float16*)(ws + WS_Y);
  float*    bnsum = (float*)(ws + WS_BNSUM);
  float*    bnssq = (float*)(ws + WS_BNSSQ);
  float*    psum  = (float*)(ws + WS_PSUM);
  float*    pssq  = (float*)(ws + WS_PSSQ);
  _Float16* gw16  = (_Float16*)(ws + WS_GW16);
  _Float16* ww16  = (_Float16*)(ws + WS_WW16);

  conv16_kernel<<<128, 256, 0, stream>>>(g_w, w_w, gw16, ww16);
  fused_pre_kernel<<<dim3(32, 16), 512, 0, stream>>>(x, gw16, g_b, phi, gpool);
  attn_kernel<<<dim3(32, 16), 256, 0, stream>>>(x, phi, gpool, yb);
  stats_partial_kernel<<<dim3(64, 16), 256, 0, stream>>>(yb, ww16, w_b, psum, pssq);
  stats_reduce_kernel<<<8, 256, 0, stream>>>(psum, pssq, bnsum, bnssq);
  wconv_bn_kernel<<<dim3(64, 16), 256, 0, stream>>>(yb, ww16, w_b, bnsum, bnssq, gamma, beta, x, out);
}

// Round 13
// 187.697 us; speedup vs baseline: 1.0817x; 1.0817x over previous
//
#include <hip/hip_runtime.h>
#include <hip/hip_bf16.h>

typedef _Float16 half8 __attribute__((ext_vector_type(8)));
typedef float f32x4 __attribute__((ext_vector_type(4)));
typedef float f32x16 __attribute__((ext_vector_type(16)));
typedef unsigned uint4e __attribute__((ext_vector_type(4)));
typedef unsigned uint2e __attribute__((ext_vector_type(2)));

#define B_ 16
#define C_ 256
#define D_ 128
#define H_ 64
#define W_ 64
#define N_ 4096   // H*W
#define M_ 1024   // (H/2)*(W/2)
#define NCH 32    // M/32 key chunks

// workspace layout (bytes)
static constexpr size_t WS_PHI   = 0;                                  // fp16 [B][M][C]   8 MB
static constexpr size_t WS_GPOOL = WS_PHI   + (size_t)B_*M_*C_*2;      // fp16 [B][D][M]   4 MB
static constexpr size_t WS_Y     = WS_GPOOL + (size_t)B_*D_*M_*2;      // fp16 [B][N][D]  16 MB
static constexpr size_t WS_BNSUM = WS_Y     + (size_t)B_*N_*D_*2;      // f32  [C]
static constexpr size_t WS_BNSSQ = WS_BNSUM + (size_t)C_*4;            // f32  [C]
static constexpr size_t WS_PSUM  = WS_BNSSQ + (size_t)C_*4;            // f32  [1024][256] 1MB
static constexpr size_t WS_PSSQ  = WS_PSUM  + (size_t)1024*256*4;      // f32  [1024][256] 1MB
static constexpr size_t WS_GW16  = WS_PSSQ  + (size_t)1024*256*4;      // fp16 [D][C] 64KB
static constexpr size_t WS_WW16  = WS_GW16  + (size_t)D_*C_*2;         // fp16 [C][D] 64KB

typedef __attribute__((address_space(3))) void lds_vt;
typedef const __attribute__((address_space(1))) void gbl_vt;

__device__ __forceinline__ void gl2lds16(const void* g, void* s) {
  __builtin_amdgcn_global_load_lds((gbl_vt*)g, (lds_vt*)s, 16, 0, 0);
}

__device__ __forceinline__ unsigned pkrtz(float a, float b) {
  auto v = __builtin_amdgcn_cvt_pkrtz(a, b);   // __fp16 ext_vector(2)
  return __builtin_bit_cast(unsigned, v);
}

// xor-32 lane exchange on the VALU pipe (permlane32_swap) instead of LDS.
__device__ __forceinline__ unsigned xor32_swap(unsigned v) {
#if __has_builtin(__builtin_amdgcn_permlane32_swap)
  auto pr = __builtin_amdgcn_permlane32_swap(v, v, false, false);
  uint2e p = __builtin_bit_cast(uint2e, pr);
  return (threadIdx.x & 32) ? p[0] : p[1];
#else
  return __shfl_xor(v, 32, 64);
#endif
}
__device__ __forceinline__ float xor32f(float v) {
  return __builtin_bit_cast(float, xor32_swap(__builtin_bit_cast(unsigned, v)));
}

// ---------------------------------------------------------------------------
// P0: convert weights to fp16 once. gw16[d][c], ww16[c][d].
// ---------------------------------------------------------------------------
__global__ __launch_bounds__(256) void conv16_kernel(
    const float* __restrict__ gw, const float* __restrict__ ww,
    _Float16* __restrict__ gw16, _Float16* __restrict__ ww16) {
  const int i = blockIdx.x*256 + threadIdx.x;   // 0..32767
  gw16[i] = (_Float16)gw[i];
  ww16[i] = (_Float16)ww[i];
}

// ---------------------------------------------------------------------------
// P1+P2 fused: LDS-staged x slab (fp16 [256c][130n] padded), coalesced float4
// staging. phi = fp16(maxpool2x2(x)); gpool = fp16(maxpool2x2(g_w*.x)+g_b).
// (verified round 10)
// ---------------------------------------------------------------------------
__global__ __launch_bounds__(512, 4) void fused_pre_kernel(
    const float* __restrict__ x, const _Float16* __restrict__ gw16,
    const float* __restrict__ g_b, _Float16* __restrict__ phi,
    _Float16* __restrict__ gpool) {
  const int i = blockIdx.x;            // image row-pair (rows 2i, 2i+1)
  const int b = blockIdx.y;
  const int t = threadIdx.x;
  const int w = t >> 6, l = t & 63, gq = (l >> 4) & 3, c16 = l & 15;
  const int wn = w & 3, wd = w >> 2;

  __shared__ _Float16 x_s[256][130];   // 65 KB; odd dword pitch -> all banks

  {
    const float* xb = x + (size_t)b*C_*N_ + (size_t)i*128;
#pragma unroll
    for (int it = 0; it < 16; ++it) {
      const int id = it*512 + t;
      const int c = id >> 5, nq = id & 31;
      float4 u = *(const float4*)(xb + (size_t)c*N_ + nq*4);
      unsigned* dst = (unsigned*)&x_s[c][nq*4];
      dst[0] = pkrtz(u.x, u.y);
      dst[1] = pkrtz(u.z, u.w);
    }
  }
  __syncthreads();

  f32x4 acc[4][2];
#pragma unroll
  for (int ds = 0; ds < 4; ++ds) {
    acc[ds][0] = (f32x4){0.f,0.f,0.f,0.f};
    acc[ds][1] = (f32x4){0.f,0.f,0.f,0.f};
  }

  const int nn0 = wn*16 + c16;
  const int mrow = i*32 + wn*8 + (c16 >> 1);

  for (int kk = 0; kk < 8; ++kk) {
    const int c0 = kk*32 + gq*8;
    half8 bf0, bf1;
#pragma unroll
    for (int j = 0; j < 8; ++j) {
      bf0[j] = x_s[c0 + j][nn0];
      bf1[j] = x_s[c0 + j][nn0 + 64];
    }
    if (wd == 0) {
      half8 pk_;
#pragma unroll
      for (int j = 0; j < 8; ++j) {
        float v = fmaxf((float)bf0[j], (float)bf1[j]);
        v = fmaxf(v, __shfl_xor(v, 1, 64));
        pk_[j] = (_Float16)v;
      }
      if (!(l & 1))
        *(half8*)(phi + ((size_t)b*M_ + mrow)*C_ + c0) = pk_;
    }
#pragma unroll
    for (int ds = 0; ds < 4; ++ds) {
      half8 af = *(const half8*)(gw16 + (size_t)((wd*4 + ds)*16 + c16)*C_ + c0);
      acc[ds][0] = __builtin_amdgcn_mfma_f32_16x16x32_f16(af, bf0, acc[ds][0], 0, 0, 0);
      acc[ds][1] = __builtin_amdgcn_mfma_f32_16x16x32_f16(af, bf1, acc[ds][1], 0, 0, 0);
    }
  }

#pragma unroll
  for (int ds = 0; ds < 4; ++ds) {
#pragma unroll
    for (int r = 0; r < 4; ++r) {
      const int d = (wd*4 + ds)*16 + gq*4 + r;
      float v = fmaxf(acc[ds][0][r], acc[ds][1][r]);
      v = fmaxf(v, __shfl_xor(v, 1, 64));
      if (!(l & 1))
        gpool[((size_t)b*D_ + d)*M_ + mrow] = (_Float16)(v + g_b[d]);
    }
  }
}

// ---------------------------------------------------------------------------
// P3: flash attention v7 — 32x32x16 MFMA (2x FLOP per LDS byte).
// 8 waves x 32 q = 256 q/block, 512 threads, grid (16,16) = 1 block/CU.
// Same tri-buffered staging/vmcnt(3)/1-barrier schedule as verified r10.
// Layouts (gfx950, measured): C/D col=lane&31 row=(reg&3)+8*(reg>>2)+4*lhi;
// A[row=l&31][k=lhi*8+j]; B[k=lhi*8+j][col=l&31].
// Swapped QK: S[m][q], q = lane dim -> softmax lane-local over 16 regs.
// ---------------------------------------------------------------------------
__global__ __launch_bounds__(512, 2) void attn_kernel(
    const float* __restrict__ x, const _Float16* __restrict__ phi,
    const _Float16* __restrict__ gpool, _Float16* __restrict__ y) {
  const int nt = blockIdx.x;           // 0..15
  const int b  = blockIdx.y;
  const int t  = threadIdx.x;
  const int w = t >> 6, l = t & 63, l31 = l & 31, lhi = l >> 5;
  const int nq = nt*256 + w*32 + l31;  // this lane's q row (lane dim)

  __shared__ alignas(16) _Float16 phi_s[3][32*256];   // 16KB x 3, addr(o16,m)=o*512+m*16
  __shared__ alignas(16) _Float16 gp_s[3][128*32];    // 8KB x 3, addr(d,om)=om*2048+(d>>6)*1024+(d&63)*16

  // Q fragments (B-operand): qf[kk][j] = x[c = kk*16 + lhi*8 + j][nq]
  half8 qf[16];
#pragma unroll
  for (int kk = 0; kk < 16; ++kk) {
    const int cb = kk*16 + lhi*8;
    half8 q;
#pragma unroll
    for (int j = 0; j < 8; ++j) q[j] = (_Float16)x[((size_t)b*C_ + cb + j)*N_ + nq];
    qf[kk] = q;
  }

  f32x16 yacc0 = 0.f, yacc1 = 0.f, yacc2 = 0.f, yacc3 = 0.f;
  float m_run = -INFINITY, l_run = 0.f;

  auto stage = [&](int buf, int ch2) {
    const int m0 = ch2 * 32;
    // phi chunk 16KB = 16 slots (2/wave). octet o = 2j+lhi, row m = l31.
#pragma unroll
    for (int jj = 0; jj < 2; ++jj) {
      const int j = w*2 + jj;
      const char* src = (const char*)phi + ((size_t)(b*M_ + m0 + l31))*512 + (2*j + lhi)*16;
      gl2lds16(src, (char*)&phi_s[buf][0] + j*1024);
    }
    // gp chunk 8KB = 8 slots (1/wave). m-octet = w>>1, d = (w&1)*64 + l.
    {
      const char* src = (const char*)gpool + (((size_t)(b*D_ + (w&1)*64 + l))*M_ + m0)*2 + (w>>1)*16;
      gl2lds16(src, (char*)&gp_s[buf][0] + w*1024);
    }
  };

  stage(0, 0);
  stage(1, 1);

  const char* pAbase = (const char*)&phi_s[0][0] + lhi*512 + l31*16;
  const char* pBbase = (const char*)&gp_s[0][0] + lhi*2048 + l31*16;

  for (int ch = 0; ch < NCH; ++ch) {
    const int cur = ch % 3;
    if (ch < NCH - 1) {
      asm volatile("s_waitcnt vmcnt(3)" ::: "memory");   // stage(ch) landed
    } else {
      asm volatile("s_waitcnt vmcnt(0)" ::: "memory");
    }
    __builtin_amdgcn_s_barrier();
    asm volatile("" ::: "memory");

    // ---- QK^T swapped: fS = S[m(reg,lhi)][q=l31], 16 kk-steps of K=16
    f32x16 fS = 0.f;
    const char* pA = pAbase + cur*16384;
    __builtin_amdgcn_s_setprio(1);
#pragma unroll
    for (int kk = 0; kk < 16; ++kk) {
      half8 a0 = *(const half8*)(pA + kk*1024);   // A[m=l31][c-octet kk*2+lhi]
      fS = __builtin_amdgcn_mfma_f32_32x32x16_f16(a0, qf[kk], fS, 0, 0, 0);
    }
    __builtin_amdgcn_s_setprio(0);

    // ---- online softmax (q lane-local; m in regs) + defer-max THR=8
    float cmax = fS[0];
#pragma unroll
    for (int i = 1; i < 16; ++i) cmax = fmaxf(cmax, fS[i]);
    cmax = fmaxf(cmax, xor32f(cmax));
    if (__any(cmax - m_run > 8.0f)) {   // slow path: rescale
      const float mn = fmaxf(m_run, cmax);
      const float sc = __expf(m_run - mn);
      m_run = mn;
      l_run *= sc;
      const int sci = __float_as_int(sc);
#pragma unroll
      for (int i = 0; i < 16; ++i) {
        const int qrow = (i & 3) + 8*(i >> 2) + 4*lhi;
        const float scn = __int_as_float(__builtin_amdgcn_ds_bpermute(4*qrow, sci));
        yacc0[i] *= scn; yacc1[i] *= scn; yacc2[i] *= scn; yacc3[i] *= scn;
      }
    }
    float p[16];
    float rs = 0.f;
#pragma unroll
    for (int i = 0; i < 16; ++i) { p[i] = __expf(fS[i] - m_run); rs += p[i]; }
    rs += xor32f(rs);
    l_run += rs;

    // ---- P -> PV A-frags. words wq[k] = fp16 pair; lhi0 holds m{2k,2k+1},
    // lhi1 holds m{2k+4 block}: w0..w3 -> m0..15 halves, w4..w7 -> m16..31.
    unsigned w0 = pkrtz(p[0],  p[1]),  w1 = pkrtz(p[2],  p[3]);
    unsigned w2 = pkrtz(p[4],  p[5]),  w3 = pkrtz(p[6],  p[7]);
    unsigned w4 = pkrtz(p[8],  p[9]),  w5 = pkrtz(p[10], p[11]);
    unsigned w6 = pkrtz(p[12], p[13]), w7 = pkrtz(p[14], p[15]);
    unsigned X0 = xor32_swap(w0), X1 = xor32_swap(w1);
    unsigned X2 = xor32_swap(w2), X3 = xor32_swap(w3);
    unsigned X4 = xor32_swap(w4), X5 = xor32_swap(w5);
    unsigned X6 = xor32_swap(w6), X7 = xor32_swap(w7);
    uint4e ua, ub;
    if (lhi == 0) {
      ua[0]=w0; ua[1]=w1; ua[2]=X0; ua[3]=X1;   // A s=0: m0..7
      ub[0]=w4; ub[1]=w5; ub[2]=X4; ub[3]=X5;   // A s=1: m16..23
    } else {
      ua[0]=X2; ua[1]=X3; ua[2]=w2; ua[3]=w3;   // A s=0: m8..15
      ub[0]=X6; ub[1]=X7; ub[2]=w6; ub[3]=w7;   // A s=1: m24..31
    }
    half8 pa0 = __builtin_bit_cast(half8, ua);
    half8 pa1 = __builtin_bit_cast(half8, ub);

    // ---- PV: y[q(reg)][d = dt*32 + l31], V b128 at om = s*2+lhi, + dt*512
    const char* pB = pBbase + cur*8192;
    __builtin_amdgcn_s_setprio(1);
#pragma unroll
    for (int dt = 0; dt < 4; ++dt) {
      half8 bv0 = *(const half8*)(pB + dt*512);          // s=0
      half8 bv1 = *(const half8*)(pB + 4096 + dt*512);   // s=1 (om+2)
      f32x16 acc = dt==0 ? yacc0 : dt==1 ? yacc1 : dt==2 ? yacc2 : yacc3;
      acc = __builtin_amdgcn_mfma_f32_32x32x16_f16(pa0, bv0, acc, 0, 0, 0);
      acc = __builtin_amdgcn_mfma_f32_32x32x16_f16(pa1, bv1, acc, 0, 0, 0);
      if (dt==0) yacc0 = acc; else if (dt==1) yacc1 = acc;
      else if (dt==2) yacc2 = acc; else yacc3 = acc;
    }
    __builtin_amdgcn_s_setprio(0);

    // ---- prefetch chunk ch+2 into buf (ch+2)%3
    if (ch + 2 < NCH) stage((ch + 2) % 3, ch + 2);
  }

  // epilogue: inv = 1/l (per-lane q=l31) -> broadcast to reg-dim q, write y
  {
    const float inv = 1.0f / l_run;
    const int invi = __float_as_int(inv);
#pragma unroll
    for (int i = 0; i < 16; ++i) {
      const int qrow = (i & 3) + 8*(i >> 2) + 4*lhi;
      const float invq = __int_as_float(__builtin_amdgcn_ds_bpermute(4*qrow, invi));
      const int n = nt*256 + w*32 + qrow;
      _Float16* yr = y + ((size_t)b*N_ + n)*D_ + l31;
      yr[0]  = (_Float16)(yacc0[i] * invq);
      yr[32] = (_Float16)(yacc1[i] * invq);
      yr[64] = (_Float16)(yacc2[i] * invq);
      yr[96] = (_Float16)(yacc3[i] * invq);
    }
  }
}

// ---------------------------------------------------------------------------
// P4a: W-conv recompute -> per-(block,channel) partial sum/sumsq. (r10)
// ---------------------------------------------------------------------------
__global__ __launch_bounds__(256) void stats_partial_kernel(
    const _Float16* __restrict__ y, const _Float16* __restrict__ ww16,
    const float* __restrict__ w_b, float* __restrict__ psum,
    float* __restrict__ pssq) {
  const int nt = blockIdx.x, b = blockIdx.y, t = threadIdx.x;
  const int w = t >> 6, l = t & 63, g = l >> 4, c16 = l & 15;
  const int n0 = nt*64;

  f32x4 acc[4][4];
#pragma unroll
  for (int a = 0; a < 4; ++a)
#pragma unroll
    for (int n = 0; n < 4; ++n) acc[a][n] = (f32x4){0.f,0.f,0.f,0.f};

#pragma unroll
  for (int kk = 0; kk < 4; ++kk) {
    const int d0 = kk*32 + g*8;
    half8 af[4];
#pragma unroll
    for (int cs = 0; cs < 4; ++cs)
      af[cs] = *(const half8*)(ww16 + (size_t)(w*64 + cs*16 + c16)*D_ + d0);
#pragma unroll
    for (int ns = 0; ns < 4; ++ns) {
      const int nn = n0 + ns*16 + c16;
      half8 bf = *(const half8*)&y[((size_t)b*N_ + nn)*D_ + d0];
#pragma unroll
      for (int cs = 0; cs < 4; ++cs)
        acc[cs][ns] = __builtin_amdgcn_mfma_f32_16x16x32_f16(af[cs], bf, acc[cs][ns], 0, 0, 0);
    }
  }

  const int blk = b*64 + nt;
#pragma unroll
  for (int cs = 0; cs < 4; ++cs)
#pragma unroll
    for (int r = 0; r < 4; ++r) {
      const int c = w*64 + cs*16 + g*4 + r;
      const float wb = w_b[c];
      float s = 0.f, q = 0.f;
#pragma unroll
      for (int ns = 0; ns < 4; ++ns) {
        const float v = acc[cs][ns][r] + wb;
        s += v; q += v*v;
      }
      s += __shfl_xor(s, 1, 64); s += __shfl_xor(s, 2, 64);
      s += __shfl_xor(s, 4, 64); s += __shfl_xor(s, 8, 64);
      q += __shfl_xor(q, 1, 64); q += __shfl_xor(q, 2, 64);
      q += __shfl_xor(q, 4, 64); q += __shfl_xor(q, 8, 64);
      if (c16 == 0) {
        psum[blk*C_ + c] = s;
        pssq[blk*C_ + c] = q;
      }
    }
}

// ---------------------------------------------------------------------------
// P4a2: reduce 1024 partials -> bnsum/bnssq. grid 8 blocks x 256t. (r10)
// ---------------------------------------------------------------------------
__global__ __launch_bounds__(256) void stats_reduce_kernel(
    const float* __restrict__ psum, const float* __restrict__ pssq,
    float* __restrict__ bnsum, float* __restrict__ bnssq) {
  const int t = threadIdx.x;
  const int ci = t & 31, bi = t >> 5;
  const int c = blockIdx.x*32 + ci;
  float s = 0.f, q = 0.f;
  for (int k = 0; k < 128; ++k) {
    const int row = bi + k*8;
    s += psum[row*C_ + c];
    q += pssq[row*C_ + c];
  }
  __shared__ float rs[8][32], rq[8][32];
  rs[bi][ci] = s; rq[bi][ci] = q;
  __syncthreads();
  if (bi == 0) {
    float S = 0.f, Q = 0.f;
#pragma unroll
    for (int k2 = 0; k2 < 8; ++k2) { S += rs[k2][ci]; Q += rq[k2][ci]; }
    bnsum[c] = S; bnssq[c] = Q;
  }
}

// ---------------------------------------------------------------------------
// P4b: W-conv recompute (fp16 y) + BatchNorm + residual -> out (r10)
// ---------------------------------------------------------------------------
__global__ __launch_bounds__(256) void wconv_bn_kernel(
    const _Float16* __restrict__ y, const _Float16* __restrict__ ww16,
    const float* __restrict__ w_b, const float* __restrict__ bnsum,
    const float* __restrict__ bnssq, const float* __restrict__ gamma,
    const float* __restrict__ beta, const float* __restrict__ x,
    float* __restrict__ out) {
  const int nt = blockIdx.x, b = blockIdx.y, t = threadIdx.x;
  const int w = t >> 6, l = t & 63, g = l >> 4, c16 = l & 15;
  const int n0 = nt*64;

  f32x4 acc[4][4];
#pragma unroll
  for (int a = 0; a < 4; ++a)
#pragma unroll
    for (int n = 0; n < 4; ++n) acc[a][n] = (f32x4){0.f,0.f,0.f,0.f};

#pragma unroll
  for (int kk = 0; kk < 4; ++kk) {
    const int d0 = kk*32 + g*8;
    half8 af[4];
#pragma unroll
    for (int cs = 0; cs < 4; ++cs)
      af[cs] = *(const half8*)(ww16 + (size_t)(w*64 + cs*16 + c16)*D_ + d0);
#pragma unroll
    for (int ns = 0; ns < 4; ++ns) {
      const int nn = n0 + ns*16 + c16;
      half8 bf = *(const half8*)&y[((size_t)b*N_ + nn)*D_ + d0];
#pragma unroll
      for (int cs = 0; cs < 4; ++cs)
        acc[cs][ns] = __builtin_amdgcn_mfma_f32_16x16x32_f16(af[cs], bf, acc[cs][ns], 0, 0, 0);
    }
  }

  const float inv_cnt = 1.0f / (float)((size_t)B_ * N_);
#pragma unroll
  for (int cs = 0; cs < 4; ++cs) {
#pragma unroll
    for (int r = 0; r < 4; ++r) {
      const int c = w*64 + cs*16 + g*4 + r;
      const float wb  = w_b[c];
      const float mean = bnsum[c] * inv_cnt;
      const float var  = bnssq[c] * inv_cnt - mean*mean;
      const float istd = rsqrtf(var + 1e-5f);
      const float ga = gamma[c], be = beta[c];
#pragma unroll
      for (int ns = 0; ns < 4; ++ns) {
        const int n = n0 + ns*16 + c16;
        const size_t idx = ((size_t)b*C_ + c)*N_ + n;
        const float v = acc[cs][ns][r] + wb;
        out[idx] = (v - mean)*istd*ga + be + x[idx];
      }
    }
  }
}

// ---------------------------------------------------------------------------
extern "C" void kernel_launch(void* const* d_in, const int* in_sizes, int n_in,
                              void* d_out, int out_size, void* d_ws, size_t ws_size,
                              hipStream_t stream) {
  const float* x     = (const float*)d_in[0];
  const float* g_w   = (const float*)d_in[1];
  const float* g_b   = (const float*)d_in[2];
  const float* w_w   = (const float*)d_in[3];
  const float* w_b   = (const float*)d_in[4];
  const float* gamma = (const float*)d_in[5];
  const float* beta  = (const float*)d_in[6];
  float* out = (float*)d_out;

  char* ws = (char*)d_ws;
  _Float16* phi   = (_Float16*)(ws + WS_PHI);
  _Float16* gpool = (_Float16*)(ws + WS_GPOOL);
  _Float16* yb    = (_Float16*)(ws + WS_Y);
  float*    bnsum = (float*)(ws + WS_BNSUM);
  float*    bnssq = (float*)(ws + WS_BNSSQ);
  float*    psum  = (float*)(ws + WS_PSUM);
  float*    pssq  = (float*)(ws + WS_PSSQ);
  _Float16* gw16  = (_Float16*)(ws + WS_GW16);
  _Float16* ww16  = (_Float16*)(ws + WS_WW16);

  conv16_kernel<<<128, 256, 0, stream>>>(g_w, w_w, gw16, ww16);
  fused_pre_kernel<<<dim3(32, 16), 512, 0, stream>>>(x, gw16, g_b, phi, gpool);
  attn_kernel<<<dim3(16, 16), 512, 0, stream>>>(x, phi, gpool, yb);
  stats_partial_kernel<<<dim3(64, 16), 256, 0, stream>>>(yb, ww16, w_b, psum, pssq);
  stats_reduce_kernel<<<8, 256, 0, stream>>>(psum, pssq, bnsum, bnssq);
  wconv_bn_kernel<<<dim3(64, 16), 256, 0, stream>>>(yb, ww16, w_b, bnsum, bnssq, gamma, beta, x, out);
}